// Round 1
// 2514.751 us; speedup vs baseline: 1.1743x; 1.1743x over previous
//
#include <hip/hip_runtime.h>

typedef __bf16 bf16x8 __attribute__((ext_vector_type(8)));
typedef float floatx4 __attribute__((ext_vector_type(4)));

__device__ __forceinline__ float u2f(unsigned short u) {
  union { unsigned int i; float f; } v; v.i = ((unsigned int)u) << 16; return v.f;
}
__device__ __forceinline__ unsigned short f2b(float f) {
  union { float f; unsigned int i; } v; v.f = f;
  unsigned int r = (v.i + 0x7fffu + ((v.i >> 16) & 1u)) >> 16;
  return (unsigned short)r;
}

// ---------------------------------------------------------------------------
// Generic GEMM: C[M,N] = A[M,K](bf16) @ W[N,K](fp32)^T + bias
// mode 0: store bf16; mode 1: relu, store bf16; mode 2: heads epilogue:
//   outF[(m*8+t)*N + n] = acc + bias[n] + t * W[n*ldw + K]   (fp32)
// Block tile 128x128, BK=32, 256 threads (4 waves, each 64x64).
// ---------------------------------------------------------------------------
#define LDS_STRIDE 48

__global__ __launch_bounds__(256) void gemm_kernel(
    const unsigned short* __restrict__ A, int lda,
    const float* __restrict__ W, int ldw,
    const float* __restrict__ bias,
    unsigned short* __restrict__ outB, float* __restrict__ outF,
    int M, int N, int K, int ldc, int mode)
{
  __shared__ unsigned short As[128 * LDS_STRIDE];
  __shared__ unsigned short Bs[128 * LDS_STRIDE];

  const int tid  = threadIdx.x;
  const int m0   = blockIdx.y * 128;
  const int n0   = blockIdx.x * 128;
  const int wave = tid >> 6;
  const int lane = tid & 63;
  const int wm   = (wave >> 1) * 64;
  const int wn   = (wave & 1) * 64;
  const int lr   = lane & 15;     // row-in-tile for frags / col for C
  const int lq   = lane >> 4;     // quad

  floatx4 acc[4][4];
#pragma unroll
  for (int i = 0; i < 4; i++)
#pragma unroll
    for (int j = 0; j < 4; j++)
      acc[i][j] = (floatx4){0.f, 0.f, 0.f, 0.f};

  for (int k0 = 0; k0 < K; k0 += 32) {
    __syncthreads();
    // stage A tile [128 x 32] bf16 : 2 x 16B per thread
#pragma unroll
    for (int i = 0; i < 2; i++) {
      int c   = tid + i * 256;
      int row = c >> 2;
      int k8  = (c & 3) * 8;
      uint4 val = {0u, 0u, 0u, 0u};
      if (m0 + row < M)
        val = *(const uint4*)(A + (size_t)(m0 + row) * lda + k0 + k8);
      *(uint4*)(&As[row * LDS_STRIDE + k8]) = val;
    }
    // stage W tile [128 x 32] fp32 -> bf16 : 4 x 4 floats per thread
#pragma unroll
    for (int i = 0; i < 4; i++) {
      int c   = tid + i * 256;
      int row = c >> 3;
      int k4  = (c & 7) * 4;
      float f0 = 0.f, f1 = 0.f, f2 = 0.f, f3 = 0.f;
      if (n0 + row < N) {
        const float* p = W + (size_t)(n0 + row) * ldw + k0 + k4;
        f0 = p[0]; f1 = p[1]; f2 = p[2]; f3 = p[3];
      }
      ushort4 pk;
      pk.x = f2b(f0); pk.y = f2b(f1); pk.z = f2b(f2); pk.w = f2b(f3);
      *(ushort4*)(&Bs[row * LDS_STRIDE + k4]) = pk;
    }
    __syncthreads();

    bf16x8 af[4], bfr[4];
#pragma unroll
    for (int t = 0; t < 4; t++) {
      af[t]  = *(const bf16x8*)(&As[(wm + t * 16 + lr) * LDS_STRIDE + lq * 8]);
      bfr[t] = *(const bf16x8*)(&Bs[(wn + t * 16 + lr) * LDS_STRIDE + lq * 8]);
    }
#pragma unroll
    for (int tm = 0; tm < 4; tm++)
#pragma unroll
      for (int tn = 0; tn < 4; tn++)
        acc[tm][tn] = __builtin_amdgcn_mfma_f32_16x16x32_bf16(
            af[tm], bfr[tn], acc[tm][tn], 0, 0, 0);
  }

  // epilogue
#pragma unroll
  for (int tm = 0; tm < 4; tm++) {
#pragma unroll
    for (int tn = 0; tn < 4; tn++) {
      int gcol = n0 + wn + tn * 16 + lr;
      if (gcol >= N) continue;
      float bs = bias[gcol];
      if (mode == 2) {
        float wl = W[(size_t)gcol * ldw + K];
#pragma unroll
        for (int r = 0; r < 4; r++) {
          int grow = m0 + wm + tm * 16 + lq * 4 + r;
          float base = acc[tm][tn][r] + bs;
          float* op = outF + ((size_t)grow * 8) * (size_t)N + gcol;
#pragma unroll
          for (int t = 0; t < 8; t++)
            op[(size_t)t * N] = base + (float)t * wl;
        }
      } else {
#pragma unroll
        for (int r = 0; r < 4; r++) {
          int grow = m0 + wm + tm * 16 + lq * 4 + r;
          if (grow < M) {
            float v = acc[tm][tn][r] + bs;
            if (mode == 1) v = fmaxf(v, 0.f);
            outB[(size_t)grow * ldc + gcol] = f2b(v);
          }
        }
      }
    }
  }
}

// ---------------------------------------------------------------------------
// MFMA attention: one block per (b,h). S=200, hd=16.
// qkv: [25600, 384] bf16 rows (q|k|v), out: [25600, 128] bf16 (heads concat)
// Q/K staged [208 x 40] bf16 (cols 16..39 zero -> zero-padded K dim for
// 16x16x32 mfma). V transposed [16][232] bf16 (cols >=200 zero).
// Scores: 13 chunk-accs in regs; softmax via shfl over the 16-lane col group;
// P restaged bf16 per wave [16][232]; PV = 7 mfmas. All strides 16B-aligned,
// <=2-way LDS bank aliasing (free per G4).
// ---------------------------------------------------------------------------
#define QKSTR 40
#define PSTR  232

__global__ __launch_bounds__(256) void attn_kernel(
    const unsigned short* __restrict__ qkv, unsigned short* __restrict__ out)
{
  __shared__ __attribute__((aligned(16))) unsigned short qsh[208 * QKSTR];
  __shared__ __attribute__((aligned(16))) unsigned short ksh[208 * QKSTR];
  __shared__ __attribute__((aligned(16))) unsigned short vsh[16 * PSTR];
  __shared__ __attribute__((aligned(16))) unsigned short psh[4][16 * PSTR];

  const int bh   = blockIdx.x;
  const int b    = bh >> 3, h = bh & 7;
  const int tid  = threadIdx.x;
  const int wave = tid >> 6;
  const int lane = tid & 63;
  const int lr   = lane & 15;
  const int lq   = lane >> 4;
  const size_t rowbase = (size_t)b * 200;

  // zero LDS: K-dim pad cols, tail rows (>=200), V/P pad cols must be 0
  for (int i = tid; i < 208 * QKSTR / 2; i += 256) {
    ((unsigned int*)qsh)[i] = 0u;
    ((unsigned int*)ksh)[i] = 0u;
  }
  for (int i = tid; i < 16 * PSTR / 2; i += 256)
    ((unsigned int*)vsh)[i] = 0u;
  for (int i = tid; i < 4 * 16 * PSTR / 2; i += 256)
    ((unsigned int*)&psh[0][0])[i] = 0u;
  __syncthreads();

  // stage q,k row-major [s][0..16), v transposed [d][s]
  for (int i = tid; i < 800; i += 256) {
    int s = i >> 2, d4 = (i & 3) * 4;
    const unsigned short* base = qkv + (rowbase + s) * 384 + h * 16 + d4;
    uint2 qv = *(const uint2*)(base);
    uint2 kv = *(const uint2*)(base + 128);
    uint2 vv = *(const uint2*)(base + 256);
    *(uint2*)&qsh[s * QKSTR + d4] = qv;
    *(uint2*)&ksh[s * QKSTR + d4] = kv;
    vsh[(d4 + 0) * PSTR + s] = (unsigned short)(vv.x & 0xffffu);
    vsh[(d4 + 1) * PSTR + s] = (unsigned short)(vv.x >> 16);
    vsh[(d4 + 2) * PSTR + s] = (unsigned short)(vv.y & 0xffffu);
    vsh[(d4 + 3) * PSTR + s] = (unsigned short)(vv.y >> 16);
  }
  __syncthreads();

  unsigned short* pw = &psh[wave][0];

  for (int t = wave; t < 13; t += 4) {
    const int q0 = t * 16;
    // Q A-frag: row = q0+lr, k(d) = lq*8 (zeros beyond d=16 come from LDS pad)
    bf16x8 qf = *(const bf16x8*)&qsh[(q0 + lr) * QKSTR + lq * 8];

    floatx4 s[13];
#pragma unroll
    for (int c = 0; c < 13; c++) {
      bf16x8 kf = *(const bf16x8*)&ksh[(c * 16 + lr) * QKSTR + lq * 8];
      s[c] = __builtin_amdgcn_mfma_f32_16x16x32_bf16(
          qf, kf, (floatx4){0.f, 0.f, 0.f, 0.f}, 0, 0, 0);
    }

    // lane holds S[q = lq*4+r][k' = c*16+lr]; mask k' >= 200, scale 1/4
    float mx[4] = {-1e30f, -1e30f, -1e30f, -1e30f};
#pragma unroll
    for (int c = 0; c < 13; c++)
#pragma unroll
      for (int r = 0; r < 4; r++) {
        float v = s[c][r] * 0.25f;
        if (c == 12 && lr >= 8) v = -1e30f;
        s[c][r] = v;
        mx[r] = fmaxf(mx[r], v);
      }
#pragma unroll
    for (int m = 1; m < 16; m <<= 1)
#pragma unroll
      for (int r = 0; r < 4; r++)
        mx[r] = fmaxf(mx[r], __shfl_xor(mx[r], m, 16));

    float sm[4] = {0.f, 0.f, 0.f, 0.f};
#pragma unroll
    for (int c = 0; c < 13; c++)
#pragma unroll
      for (int r = 0; r < 4; r++) {
        float e = __expf(s[c][r] - mx[r]);
        s[c][r] = e;
        sm[r] += e;
      }
#pragma unroll
    for (int m = 1; m < 16; m <<= 1)
#pragma unroll
      for (int r = 0; r < 4; r++)
        sm[r] += __shfl_xor(sm[r], m, 16);

    // write P (bf16) in PV A-frag layout: row = q-in-tile, col = k'
#pragma unroll
    for (int c = 0; c < 13; c++)
#pragma unroll
      for (int r = 0; r < 4; r++)
        pw[(lq * 4 + r) * PSTR + c * 16 + lr] = f2b(s[c][r]);

    // PV: O[16 x 16] = P[16 x 224] @ Vt rows (d), fp32 acc
    floatx4 o = {0.f, 0.f, 0.f, 0.f};
#pragma unroll
    for (int ks = 0; ks < 7; ks++) {
      bf16x8 pf = *(const bf16x8*)&pw[lr * PSTR + ks * 32 + lq * 8];
      bf16x8 vf = *(const bf16x8*)&vsh[lr * PSTR + ks * 32 + lq * 8];
      o = __builtin_amdgcn_mfma_f32_16x16x32_bf16(pf, vf, o, 0, 0, 0);
    }

    // O rows = lq*4+r (same mapping as sm[r]); col = d = lr
#pragma unroll
    for (int r = 0; r < 4; r++) {
      int q = q0 + lq * 4 + r;
      if (q < 200)
        out[(rowbase + q) * 128 + h * 16 + lr] = f2b(o[r] / sm[r]);
    }
  }
}

// ---------------------------------------------------------------------------
// Fused FFN: out[M,128] = relu(x[M,128] @ W1[2048,128]^T + b1) @ W2[128,2048]^T + b2
// 64-row M-tile per block (grid 400), 32 chunks of 64 mid-cols. mid stays in
// LDS (wave-private rows -> no barrier between FFN1 write and FFN2 read).
// x frags held in registers. LDS 45 KB -> 3 blocks/CU.
// ---------------------------------------------------------------------------
__global__ __launch_bounds__(256) void ffn_kernel(
    const unsigned short* __restrict__ x,
    const float* __restrict__ W1, const float* __restrict__ b1,
    const float* __restrict__ W2, const float* __restrict__ b2,
    unsigned short* __restrict__ out)
{
  __shared__ __attribute__((aligned(16))) unsigned short w1s[64 * 136];
  __shared__ __attribute__((aligned(16))) unsigned short w2s[128 * 72];
  __shared__ __attribute__((aligned(16))) unsigned short mids[64 * 72];

  const int tid  = threadIdx.x;
  const int wave = tid >> 6;
  const int lane = tid & 63;
  const int lr   = lane & 15;
  const int lq   = lane >> 4;
  const int m0   = blockIdx.x * 64;
  const int wm   = wave * 16;

  // x fragments: wave's 16 rows, K = 128 (4 k-steps)
  bf16x8 af[4];
#pragma unroll
  for (int ks = 0; ks < 4; ks++)
    af[ks] = *(const bf16x8*)(x + (size_t)(m0 + wm + lr) * 128 + ks * 32 + lq * 8);

  floatx4 acc[8];
#pragma unroll
  for (int i = 0; i < 8; i++) acc[i] = (floatx4){0.f, 0.f, 0.f, 0.f};

  for (int c = 0; c < 32; c++) {
    const int f0 = c * 64;
    __syncthreads();
    // stage W1 chunk [64 x 128] fp32 -> bf16
#pragma unroll
    for (int j = 0; j < 8; j++) {
      int u = tid + j * 256;            // float4 units, 2048 total
      int row = u >> 5, c4 = (u & 31) * 4;
      const float* p = W1 + (size_t)(f0 + row) * 128 + c4;
      float4 v = *(const float4*)p;
      ushort4 pk = { f2b(v.x), f2b(v.y), f2b(v.z), f2b(v.w) };
      *(ushort4*)&w1s[row * 136 + c4] = pk;
    }
    // stage W2 chunk [128 rows x 64 cols] fp32 -> bf16
#pragma unroll
    for (int j = 0; j < 8; j++) {
      int u = tid + j * 256;
      int row = u >> 4, c4 = (u & 15) * 4;
      const float* p = W2 + (size_t)row * 2048 + f0 + c4;
      float4 v = *(const float4*)p;
      ushort4 pk = { f2b(v.x), f2b(v.y), f2b(v.z), f2b(v.w) };
      *(ushort4*)&w2s[row * 72 + c4] = pk;
    }
    __syncthreads();

    // FFN1: mid[wm..wm+16][0..64] = relu(x @ W1c^T + b1c)
    floatx4 macc[4];
#pragma unroll
    for (int tn = 0; tn < 4; tn++) macc[tn] = (floatx4){0.f, 0.f, 0.f, 0.f};
#pragma unroll
    for (int ks = 0; ks < 4; ks++)
#pragma unroll
      for (int tn = 0; tn < 4; tn++) {
        bf16x8 wf = *(const bf16x8*)&w1s[(tn * 16 + lr) * 136 + ks * 32 + lq * 8];
        macc[tn] = __builtin_amdgcn_mfma_f32_16x16x32_bf16(af[ks], wf, macc[tn], 0, 0, 0);
      }
#pragma unroll
    for (int tn = 0; tn < 4; tn++) {
      float bb = b1[f0 + tn * 16 + lr];
#pragma unroll
      for (int r = 0; r < 4; r++) {
        float v = fmaxf(macc[tn][r] + bb, 0.f);
        mids[(wm + lq * 4 + r) * 72 + tn * 16 + lr] = f2b(v);
      }
    }
    // FFN2 accumulate (wave-private mid rows; same-wave LDS dep only)
#pragma unroll
    for (int ks = 0; ks < 2; ks++) {
      bf16x8 mf = *(const bf16x8*)&mids[(wm + lr) * 72 + ks * 32 + lq * 8];
#pragma unroll
      for (int tn = 0; tn < 8; tn++) {
        bf16x8 wf = *(const bf16x8*)&w2s[(tn * 16 + lr) * 72 + ks * 32 + lq * 8];
        acc[tn] = __builtin_amdgcn_mfma_f32_16x16x32_bf16(mf, wf, acc[tn], 0, 0, 0);
      }
    }
  }

  // epilogue: out = acc + b2 (bf16)
#pragma unroll
  for (int tn = 0; tn < 8; tn++) {
    float bb = b2[tn * 16 + lr];
#pragma unroll
    for (int r = 0; r < 4; r++) {
      int row = m0 + wm + lq * 4 + r;
      out[(size_t)row * 128 + tn * 16 + lr] = f2b(acc[tn][r] + bb);
    }
  }
}

// ---------------------------------------------------------------------------
// Fused residual + LayerNorm (in place on x): x = LN(x + sub) * g + b
// one wave per row (128 elems, 2 per lane), 4 rows per block
// ---------------------------------------------------------------------------
__global__ __launch_bounds__(256) void ln_kernel(
    unsigned short* __restrict__ x, const unsigned short* __restrict__ sub,
    const float* __restrict__ g, const float* __restrict__ b)
{
  int row  = blockIdx.x * 4 + (threadIdx.x >> 6);
  int lane = threadIdx.x & 63;
  size_t base = (size_t)row * 128;
  int d0 = lane * 2, d1 = d0 + 1;
  float v0 = u2f(x[base + d0]) + u2f(sub[base + d0]);
  float v1 = u2f(x[base + d1]) + u2f(sub[base + d1]);
  float s  = v0 + v1;
  float ss = v0 * v0 + v1 * v1;
  for (int m = 1; m < 64; m <<= 1) {
    s  += __shfl_xor(s, m, 64);
    ss += __shfl_xor(ss, m, 64);
  }
  float mean = s * (1.f / 128.f);
  float var  = ss * (1.f / 128.f) - mean * mean;
  float r    = rsqrtf(var + 1e-5f);
  x[base + d0] = f2b((v0 - mean) * r * g[d0] + b[d0]);
  x[base + d1] = f2b((v1 - mean) * r * g[d1] + b[d1]);
}

// ---------------------------------------------------------------------------
__global__ __launch_bounds__(128) void gather_kernel(
    const int* __restrict__ ids, const float* __restrict__ table,
    unsigned short* __restrict__ x)
{
  int rid = blockIdx.x;
  int d   = threadIdx.x;
  int id  = ids[rid];
  x[(size_t)rid * 128 + d] = f2b(table[(size_t)id * 128 + d]);
}

__global__ __launch_bounds__(128) void pool_kernel(
    const unsigned short* __restrict__ x, unsigned short* __restrict__ hcat,
    int col0)
{
  int b = blockIdx.x;
  int d = threadIdx.x;
  float s = 0.f;
  for (int t = 0; t < 200; t++)
    s += u2f(x[(size_t)(b * 200 + t) * 128 + d]);
  hcat[b * 256 + col0 + d] = f2b(s * (1.f / 200.f));
}

// ---------------------------------------------------------------------------
static void gemm(hipStream_t st, const unsigned short* A, int lda,
                 const float* W, int ldw, const float* bias,
                 unsigned short* outB, float* outF,
                 int M, int N, int K, int ldc, int mode)
{
  dim3 grid((N + 127) / 128, (M + 127) / 128);
  gemm_kernel<<<grid, dim3(256), 0, st>>>(A, lda, W, ldw, bias, outB, outF,
                                          M, N, K, ldc, mode);
}

extern "C" void kernel_launch(void* const* d_in, const int* in_sizes, int n_in,
                              void* d_out, int out_size, void* d_ws, size_t ws_size,
                              hipStream_t stream)
{
  const int*   tab_ids     = (const int*)d_in[0];
  const int*   idx_ids     = (const int*)d_in[1];
  const float* table_embed = (const float*)d_in[2];
  const float* idx_embed   = (const float*)d_in[3];
  const float* Wqkv = (const float*)d_in[4];
  const float* bqkv = (const float*)d_in[5];
  const float* Wo   = (const float*)d_in[6];
  const float* bo   = (const float*)d_in[7];
  const float* ln1g = (const float*)d_in[8];
  const float* ln1b = (const float*)d_in[9];
  const float* W1   = (const float*)d_in[10];
  const float* b1   = (const float*)d_in[11];
  const float* W2   = (const float*)d_in[12];
  const float* b2   = (const float*)d_in[13];
  const float* ln2g = (const float*)d_in[14];
  const float* ln2b = (const float*)d_in[15];
  const float* Wlin = (const float*)d_in[16];
  const float* blin = (const float*)d_in[17];
  const float* Wtab = (const float*)d_in[18];
  const float* btab = (const float*)d_in[19];
  const float* Widx = (const float*)d_in[20];
  const float* bidx = (const float*)d_in[21];
  float* out = (float*)d_out;
  char*  ws  = (char*)d_ws;

  const size_t off_x    = 0;                 // 25600*128 bf16 = 6,553,600
  const size_t off_qkv  = 6553600;           // 25600*384 bf16 = 19,660,800 (o2 aliases)
  const size_t off_attn = 26214400;          // 25600*128 bf16
  const size_t off_hcat = 32768000;          // 128*256 bf16
  const size_t off_h    = off_hcat + 65536;  // 128*512 bf16

  unsigned short* x    = (unsigned short*)(ws + off_x);
  unsigned short* qkv  = (unsigned short*)(ws + off_qkv);
  unsigned short* o2   = qkv;                       // reuse (qkv dead after attn)
  unsigned short* attn = (unsigned short*)(ws + off_attn);
  unsigned short* hcat = (unsigned short*)(ws + off_hcat);
  unsigned short* h    = (unsigned short*)(ws + off_h);

  for (int e = 0; e < 2; e++) {
    gather_kernel<<<25600, 128, 0, stream>>>(
        e == 0 ? tab_ids : idx_ids,
        e == 0 ? table_embed : idx_embed, x);
    for (int l = 0; l < 2; l++) {
      int pi = e * 2 + l;
      gemm(stream, x, 128, Wqkv + (size_t)pi * 384 * 128, 128,
           bqkv + (size_t)pi * 384, qkv, nullptr, 25600, 384, 128, 384, 0);
      attn_kernel<<<1024, 256, 0, stream>>>(qkv, attn);
      gemm(stream, attn, 128, Wo + (size_t)pi * 128 * 128, 128,
           bo + (size_t)pi * 128, o2, nullptr, 25600, 128, 128, 128, 0);
      ln_kernel<<<6400, 256, 0, stream>>>(x, o2, ln1g + pi * 128, ln1b + pi * 128);
      ffn_kernel<<<400, 256, 0, stream>>>(
          x, W1 + (size_t)pi * 2048 * 128, b1 + (size_t)pi * 2048,
          W2 + (size_t)pi * 128 * 2048, b2 + (size_t)pi * 128, o2);
      ln_kernel<<<6400, 256, 0, stream>>>(x, o2, ln2g + pi * 128, ln2b + pi * 128);
    }
    pool_kernel<<<128, 128, 0, stream>>>(x, hcat, e * 128);
  }

  gemm(stream, hcat, 256, Wlin, 256, blin, h, nullptr, 128, 512, 256, 512, 1);
  gemm(stream, h, 512, Wtab, 513, btab, nullptr, out,           128, 1000,   512, 1000,   2);
  gemm(stream, h, 512, Widx, 513, bidx, nullptr, out + 1024000, 128, 100000, 512, 100000, 2);
}

// Round 2
// 1556.988 us; speedup vs baseline: 1.8967x; 1.6151x over previous
//
#include <hip/hip_runtime.h>

typedef __bf16 bf16x8 __attribute__((ext_vector_type(8)));
typedef float floatx4 __attribute__((ext_vector_type(4)));

__device__ __forceinline__ float u2f(unsigned short u) {
  union { unsigned int i; float f; } v; v.i = ((unsigned int)u) << 16; return v.f;
}
__device__ __forceinline__ unsigned short f2b(float f) {
  union { float f; unsigned int i; } v; v.f = f;
  unsigned int r = (v.i + 0x7fffu + ((v.i >> 16) & 1u)) >> 16;
  return (unsigned short)r;
}

__device__ __forceinline__ void gl16(const void* g, void* l) {
  __builtin_amdgcn_global_load_lds(
      (const __attribute__((address_space(1))) unsigned int*)g,
      (__attribute__((address_space(3))) unsigned int*)l, 16, 0, 0);
}

// ---------------------------------------------------------------------------
// Generic GEMM: C[M,N] = A[M,K](bf16) @ W[N,K](fp32)^T + bias
// mode 0: store bf16; mode 1: relu, store bf16; mode 2: heads epilogue:
//   outF[(m*8+t)*N + n] = acc + bias[n] + t * W[n*ldw + K]   (fp32)
// Block tile 128x128, BK=32, 256 threads (4 waves, each 64x64).
// ---------------------------------------------------------------------------
#define LDS_STRIDE 48

__global__ __launch_bounds__(256) void gemm_kernel(
    const unsigned short* __restrict__ A, int lda,
    const float* __restrict__ W, int ldw,
    const float* __restrict__ bias,
    unsigned short* __restrict__ outB, float* __restrict__ outF,
    int M, int N, int K, int ldc, int mode)
{
  __shared__ unsigned short As[128 * LDS_STRIDE];
  __shared__ unsigned short Bs[128 * LDS_STRIDE];

  const int tid  = threadIdx.x;
  const int m0   = blockIdx.y * 128;
  const int n0   = blockIdx.x * 128;
  const int wave = tid >> 6;
  const int lane = tid & 63;
  const int wm   = (wave >> 1) * 64;
  const int wn   = (wave & 1) * 64;
  const int lr   = lane & 15;     // row-in-tile for frags / col for C
  const int lq   = lane >> 4;     // quad

  floatx4 acc[4][4];
#pragma unroll
  for (int i = 0; i < 4; i++)
#pragma unroll
    for (int j = 0; j < 4; j++)
      acc[i][j] = (floatx4){0.f, 0.f, 0.f, 0.f};

  for (int k0 = 0; k0 < K; k0 += 32) {
    __syncthreads();
    // stage A tile [128 x 32] bf16 : 2 x 16B per thread
#pragma unroll
    for (int i = 0; i < 2; i++) {
      int c   = tid + i * 256;
      int row = c >> 2;
      int k8  = (c & 3) * 8;
      uint4 val = {0u, 0u, 0u, 0u};
      if (m0 + row < M)
        val = *(const uint4*)(A + (size_t)(m0 + row) * lda + k0 + k8);
      *(uint4*)(&As[row * LDS_STRIDE + k8]) = val;
    }
    // stage W tile [128 x 32] fp32 -> bf16 : 4 x 4 floats per thread
#pragma unroll
    for (int i = 0; i < 4; i++) {
      int c   = tid + i * 256;
      int row = c >> 3;
      int k4  = (c & 7) * 4;
      float f0 = 0.f, f1 = 0.f, f2 = 0.f, f3 = 0.f;
      if (n0 + row < N) {
        const float* p = W + (size_t)(n0 + row) * ldw + k0 + k4;
        f0 = p[0]; f1 = p[1]; f2 = p[2]; f3 = p[3];
      }
      ushort4 pk;
      pk.x = f2b(f0); pk.y = f2b(f1); pk.z = f2b(f2); pk.w = f2b(f3);
      *(ushort4*)(&Bs[row * LDS_STRIDE + k4]) = pk;
    }
    __syncthreads();

    bf16x8 af[4], bfr[4];
#pragma unroll
    for (int t = 0; t < 4; t++) {
      af[t]  = *(const bf16x8*)(&As[(wm + t * 16 + lr) * LDS_STRIDE + lq * 8]);
      bfr[t] = *(const bf16x8*)(&Bs[(wn + t * 16 + lr) * LDS_STRIDE + lq * 8]);
    }
#pragma unroll
    for (int tm = 0; tm < 4; tm++)
#pragma unroll
      for (int tn = 0; tn < 4; tn++)
        acc[tm][tn] = __builtin_amdgcn_mfma_f32_16x16x32_bf16(
            af[tm], bfr[tn], acc[tm][tn], 0, 0, 0);
  }

  // epilogue
#pragma unroll
  for (int tm = 0; tm < 4; tm++) {
#pragma unroll
    for (int tn = 0; tn < 4; tn++) {
      int gcol = n0 + wn + tn * 16 + lr;
      if (gcol >= N) continue;
      float bs = bias[gcol];
      if (mode == 2) {
        float wl = W[(size_t)gcol * ldw + K];
#pragma unroll
        for (int r = 0; r < 4; r++) {
          int grow = m0 + wm + tm * 16 + lq * 4 + r;
          float base = acc[tm][tn][r] + bs;
          float* op = outF + ((size_t)grow * 8) * (size_t)N + gcol;
#pragma unroll
          for (int t = 0; t < 8; t++)
            op[(size_t)t * N] = base + (float)t * wl;
        }
      } else {
#pragma unroll
        for (int r = 0; r < 4; r++) {
          int grow = m0 + wm + tm * 16 + lq * 4 + r;
          if (grow < M) {
            float v = acc[tm][tn][r] + bs;
            if (mode == 1) v = fmaxf(v, 0.f);
            outB[(size_t)grow * ldc + gcol] = f2b(v);
          }
        }
      }
    }
  }
}

// ---------------------------------------------------------------------------
// MFMA attention: one block per (b,h). S=200, hd=16.  (unchanged)
// ---------------------------------------------------------------------------
#define QKSTR 40
#define PSTR  232

__global__ __launch_bounds__(256) void attn_kernel(
    const unsigned short* __restrict__ qkv, unsigned short* __restrict__ out)
{
  __shared__ __attribute__((aligned(16))) unsigned short qsh[208 * QKSTR];
  __shared__ __attribute__((aligned(16))) unsigned short ksh[208 * QKSTR];
  __shared__ __attribute__((aligned(16))) unsigned short vsh[16 * PSTR];
  __shared__ __attribute__((aligned(16))) unsigned short psh[4][16 * PSTR];

  const int bh   = blockIdx.x;
  const int b    = bh >> 3, h = bh & 7;
  const int tid  = threadIdx.x;
  const int wave = tid >> 6;
  const int lane = tid & 63;
  const int lr   = lane & 15;
  const int lq   = lane >> 4;
  const size_t rowbase = (size_t)b * 200;

  for (int i = tid; i < 208 * QKSTR / 2; i += 256) {
    ((unsigned int*)qsh)[i] = 0u;
    ((unsigned int*)ksh)[i] = 0u;
  }
  for (int i = tid; i < 16 * PSTR / 2; i += 256)
    ((unsigned int*)vsh)[i] = 0u;
  for (int i = tid; i < 4 * 16 * PSTR / 2; i += 256)
    ((unsigned int*)&psh[0][0])[i] = 0u;
  __syncthreads();

  for (int i = tid; i < 800; i += 256) {
    int s = i >> 2, d4 = (i & 3) * 4;
    const unsigned short* base = qkv + (rowbase + s) * 384 + h * 16 + d4;
    uint2 qv = *(const uint2*)(base);
    uint2 kv = *(const uint2*)(base + 128);
    uint2 vv = *(const uint2*)(base + 256);
    *(uint2*)&qsh[s * QKSTR + d4] = qv;
    *(uint2*)&ksh[s * QKSTR + d4] = kv;
    vsh[(d4 + 0) * PSTR + s] = (unsigned short)(vv.x & 0xffffu);
    vsh[(d4 + 1) * PSTR + s] = (unsigned short)(vv.x >> 16);
    vsh[(d4 + 2) * PSTR + s] = (unsigned short)(vv.y & 0xffffu);
    vsh[(d4 + 3) * PSTR + s] = (unsigned short)(vv.y >> 16);
  }
  __syncthreads();

  unsigned short* pw = &psh[wave][0];

  for (int t = wave; t < 13; t += 4) {
    const int q0 = t * 16;
    bf16x8 qf = *(const bf16x8*)&qsh[(q0 + lr) * QKSTR + lq * 8];

    floatx4 s[13];
#pragma unroll
    for (int c = 0; c < 13; c++) {
      bf16x8 kf = *(const bf16x8*)&ksh[(c * 16 + lr) * QKSTR + lq * 8];
      s[c] = __builtin_amdgcn_mfma_f32_16x16x32_bf16(
          qf, kf, (floatx4){0.f, 0.f, 0.f, 0.f}, 0, 0, 0);
    }

    float mx[4] = {-1e30f, -1e30f, -1e30f, -1e30f};
#pragma unroll
    for (int c = 0; c < 13; c++)
#pragma unroll
      for (int r = 0; r < 4; r++) {
        float v = s[c][r] * 0.25f;
        if (c == 12 && lr >= 8) v = -1e30f;
        s[c][r] = v;
        mx[r] = fmaxf(mx[r], v);
      }
#pragma unroll
    for (int m = 1; m < 16; m <<= 1)
#pragma unroll
      for (int r = 0; r < 4; r++)
        mx[r] = fmaxf(mx[r], __shfl_xor(mx[r], m, 16));

    float sm[4] = {0.f, 0.f, 0.f, 0.f};
#pragma unroll
    for (int c = 0; c < 13; c++)
#pragma unroll
      for (int r = 0; r < 4; r++) {
        float e = __expf(s[c][r] - mx[r]);
        s[c][r] = e;
        sm[r] += e;
      }
#pragma unroll
    for (int m = 1; m < 16; m <<= 1)
#pragma unroll
      for (int r = 0; r < 4; r++)
        sm[r] += __shfl_xor(sm[r], m, 16);

#pragma unroll
    for (int c = 0; c < 13; c++)
#pragma unroll
      for (int r = 0; r < 4; r++)
        pw[(lq * 4 + r) * PSTR + c * 16 + lr] = f2b(s[c][r]);

    floatx4 o = {0.f, 0.f, 0.f, 0.f};
#pragma unroll
    for (int ks = 0; ks < 7; ks++) {
      bf16x8 pf = *(const bf16x8*)&pw[lr * PSTR + ks * 32 + lq * 8];
      bf16x8 vf = *(const bf16x8*)&vsh[lr * PSTR + ks * 32 + lq * 8];
      o = __builtin_amdgcn_mfma_f32_16x16x32_bf16(pf, vf, o, 0, 0, 0);
    }

#pragma unroll
    for (int r = 0; r < 4; r++) {
      int q = q0 + lq * 4 + r;
      if (q < 200)
        out[(rowbase + q) * 128 + h * 16 + lr] = f2b(o[r] / sm[r]);
    }
  }
}

// ---------------------------------------------------------------------------
// Weight prepack for fused FFN: per (layer, chunk of 64 mid-cols) build the
// exact bf16 LDS image (strides baked in) so ffn_kernel can DMA it linearly.
// chunk image (ushort units, 18048 = 36096 B):
//   [0, 64*136)           W1c rows f(0..63) x cols k(0..127), stride 136
//   [8704, 8704+128*72)   W2c rows n(0..127) x cols j(0..63), stride 72
//   [17920, 18048)        b1c: 64 floats
// ---------------------------------------------------------------------------
#define CHIM 18048

__global__ __launch_bounds__(256) void prep_kernel(
    const float* __restrict__ W1, const float* __restrict__ b1,
    const float* __restrict__ W2, unsigned short* __restrict__ img)
{
  const int blk = blockIdx.x;         // pi*32 + c
  const int pi  = blk >> 5, c = blk & 31;
  const int tid = threadIdx.x;
  unsigned short* o = img + (size_t)blk * CHIM;
  const float* w1 = W1 + ((size_t)pi * 2048 + c * 64) * 128;
  const float* w2 = W2 + (size_t)pi * 128 * 2048 + c * 64;

  for (int u = tid; u < 64 * 34; u += 256) {
    int row = u / 34, c4 = (u % 34) * 4;
    ushort4 pk = {0, 0, 0, 0};
    if (c4 < 128) {
      const float* p = w1 + row * 128 + c4;
      pk.x = f2b(p[0]); pk.y = f2b(p[1]); pk.z = f2b(p[2]); pk.w = f2b(p[3]);
    }
    *(ushort4*)&o[row * 136 + c4] = pk;
  }
  for (int u = tid; u < 128 * 18; u += 256) {
    int row = u / 18, c4 = (u % 18) * 4;
    ushort4 pk = {0, 0, 0, 0};
    if (c4 < 64) {
      const float* p = w2 + (size_t)row * 2048 + c4;
      pk.x = f2b(p[0]); pk.y = f2b(p[1]); pk.z = f2b(p[2]); pk.w = f2b(p[3]);
    }
    *(ushort4*)&o[8704 + row * 72 + c4] = pk;
  }
  if (tid < 64)
    ((float*)(o + 17920))[tid] = b1[(size_t)pi * 2048 + c * 64 + tid];
}

// ---------------------------------------------------------------------------
// Fused FFN v2: out[M,128] = relu(x @ W1^T + b1) @ W2^T + b2
// 64-row M-tile (grid 400), 32 chunks of 64 mid-cols. Weights arrive as
// prepacked bf16 chunk images via global_load_lds (9 x 16B per thread),
// double-buffered with counted vmcnt(9) + raw s_barrier (no vmcnt-0 drain
// in the main loop). mids stays wave-private in LDS. 79.5 KB -> 2 blk/CU.
// ---------------------------------------------------------------------------
__global__ __launch_bounds__(256) void ffn_kernel(
    const unsigned short* __restrict__ x,
    const unsigned short* __restrict__ wimg,   // this layer: 32 * CHIM ushorts
    const float* __restrict__ b2,
    unsigned short* __restrict__ out)
{
  __shared__ __attribute__((aligned(16))) unsigned short wbuf[2][CHIM];
  __shared__ __attribute__((aligned(16))) unsigned short mids[64 * 72];

  const int tid  = threadIdx.x;
  const int wave = tid >> 6;
  const int lane = tid & 63;
  const int lr   = lane & 15;
  const int lq   = lane >> 4;
  const int m0   = blockIdx.x * 64;
  const int wm   = wave * 16;

  // x fragments: wave's 16 rows, K = 128 (4 k-steps)
  bf16x8 af[4];
#pragma unroll
  for (int ks = 0; ks < 4; ks++)
    af[ks] = *(const bf16x8*)(x + (size_t)(m0 + wm + lr) * 128 + ks * 32 + lq * 8);

  floatx4 acc[8];
#pragma unroll
  for (int i = 0; i < 8; i++) acc[i] = (floatx4){0.f, 0.f, 0.f, 0.f};

  // prologue: stage chunk 0 into buf 0 (9 x 16B per thread, 2256 units total)
  {
    const unsigned short* src = wimg;
#pragma unroll
    for (int i = 0; i < 9; i++) {
      int u = tid + i * 256;
      if (u < 2256) gl16(src + (size_t)u * 8, &wbuf[0][(size_t)u * 8]);
    }
  }

  for (int c = 0; c < 32; c++) {
    if (c + 1 < 32) {
      const unsigned short* src = wimg + (size_t)(c + 1) * CHIM;
      unsigned short* dst = &wbuf[(c + 1) & 1][0];
#pragma unroll
      for (int i = 0; i < 9; i++) {
        int u = tid + i * 256;
        if (u < 2256) gl16(src + (size_t)u * 8, dst + (size_t)u * 8);
      }
      asm volatile("s_waitcnt vmcnt(9)" ::: "memory");   // chunk c landed
    } else {
      asm volatile("s_waitcnt vmcnt(0)" ::: "memory");
    }
    __builtin_amdgcn_s_barrier();
    __builtin_amdgcn_sched_barrier(0);

    const unsigned short* wb = &wbuf[c & 1][0];

    // FFN1: mid[wm..wm+16][0..64] = relu(x @ W1c^T + b1c)
    floatx4 macc[4];
#pragma unroll
    for (int tn = 0; tn < 4; tn++) macc[tn] = (floatx4){0.f, 0.f, 0.f, 0.f};
#pragma unroll
    for (int ks = 0; ks < 4; ks++)
#pragma unroll
      for (int tn = 0; tn < 4; tn++) {
        bf16x8 wf = *(const bf16x8*)&wb[(tn * 16 + lr) * 136 + ks * 32 + lq * 8];
        macc[tn] = __builtin_amdgcn_mfma_f32_16x16x32_bf16(af[ks], wf, macc[tn], 0, 0, 0);
      }
    const float* b1c = (const float*)(wb + 17920);
#pragma unroll
    for (int tn = 0; tn < 4; tn++) {
      float bb = b1c[tn * 16 + lr];
#pragma unroll
      for (int r = 0; r < 4; r++) {
        float v = fmaxf(macc[tn][r] + bb, 0.f);
        mids[(wm + lq * 4 + r) * 72 + tn * 16 + lr] = f2b(v);
      }
    }
    // FFN2 accumulate (wave-private mid rows; same-wave LDS dep only)
#pragma unroll
    for (int ks = 0; ks < 2; ks++) {
      bf16x8 mf = *(const bf16x8*)&mids[(wm + lr) * 72 + ks * 32 + lq * 8];
#pragma unroll
      for (int tn = 0; tn < 8; tn++) {
        bf16x8 wf = *(const bf16x8*)&wb[8704 + (tn * 16 + lr) * 72 + ks * 32 + lq * 8];
        acc[tn] = __builtin_amdgcn_mfma_f32_16x16x32_bf16(mf, wf, acc[tn], 0, 0, 0);
      }
    }
    __builtin_amdgcn_s_barrier();   // all waves done reading wbuf[c&1]
  }

  // epilogue: out = acc + b2 (bf16)
#pragma unroll
  for (int tn = 0; tn < 8; tn++) {
    float bb = b2[tn * 16 + lr];
#pragma unroll
    for (int r = 0; r < 4; r++) {
      int row = m0 + wm + lq * 4 + r;
      out[(size_t)row * 128 + tn * 16 + lr] = f2b(acc[tn][r] + bb);
    }
  }
}

// ---------------------------------------------------------------------------
// Fused residual + LayerNorm (in place on x): x = LN(x + sub) * g + b
// ---------------------------------------------------------------------------
__global__ __launch_bounds__(256) void ln_kernel(
    unsigned short* __restrict__ x, const unsigned short* __restrict__ sub,
    const float* __restrict__ g, const float* __restrict__ b)
{
  int row  = blockIdx.x * 4 + (threadIdx.x >> 6);
  int lane = threadIdx.x & 63;
  size_t base = (size_t)row * 128;
  int d0 = lane * 2, d1 = d0 + 1;
  float v0 = u2f(x[base + d0]) + u2f(sub[base + d0]);
  float v1 = u2f(x[base + d1]) + u2f(sub[base + d1]);
  float s  = v0 + v1;
  float ss = v0 * v0 + v1 * v1;
  for (int m = 1; m < 64; m <<= 1) {
    s  += __shfl_xor(s, m, 64);
    ss += __shfl_xor(ss, m, 64);
  }
  float mean = s * (1.f / 128.f);
  float var  = ss * (1.f / 128.f) - mean * mean;
  float r    = rsqrtf(var + 1e-5f);
  x[base + d0] = f2b((v0 - mean) * r * g[d0] + b[d0]);
  x[base + d1] = f2b((v1 - mean) * r * g[d1] + b[d1]);
}

// ---------------------------------------------------------------------------
__global__ __launch_bounds__(128) void gather_kernel(
    const int* __restrict__ ids, const float* __restrict__ table,
    unsigned short* __restrict__ x)
{
  int rid = blockIdx.x;
  int d   = threadIdx.x;
  int id  = ids[rid];
  x[(size_t)rid * 128 + d] = f2b(table[(size_t)id * 128 + d]);
}

__global__ __launch_bounds__(128) void pool_kernel(
    const unsigned short* __restrict__ x, unsigned short* __restrict__ hcat,
    int col0)
{
  int b = blockIdx.x;
  int d = threadIdx.x;
  float s = 0.f;
  for (int t = 0; t < 200; t++)
    s += u2f(x[(size_t)(b * 200 + t) * 128 + d]);
  hcat[b * 256 + col0 + d] = f2b(s * (1.f / 200.f));
}

// ---------------------------------------------------------------------------
static void gemm(hipStream_t st, const unsigned short* A, int lda,
                 const float* W, int ldw, const float* bias,
                 unsigned short* outB, float* outF,
                 int M, int N, int K, int ldc, int mode)
{
  dim3 grid((N + 127) / 128, (M + 127) / 128);
  gemm_kernel<<<grid, dim3(256), 0, st>>>(A, lda, W, ldw, bias, outB, outF,
                                          M, N, K, ldc, mode);
}

extern "C" void kernel_launch(void* const* d_in, const int* in_sizes, int n_in,
                              void* d_out, int out_size, void* d_ws, size_t ws_size,
                              hipStream_t stream)
{
  const int*   tab_ids     = (const int*)d_in[0];
  const int*   idx_ids     = (const int*)d_in[1];
  const float* table_embed = (const float*)d_in[2];
  const float* idx_embed   = (const float*)d_in[3];
  const float* Wqkv = (const float*)d_in[4];
  const float* bqkv = (const float*)d_in[5];
  const float* Wo   = (const float*)d_in[6];
  const float* bo   = (const float*)d_in[7];
  const float* ln1g = (const float*)d_in[8];
  const float* ln1b = (const float*)d_in[9];
  const float* W1   = (const float*)d_in[10];
  const float* b1   = (const float*)d_in[11];
  const float* W2   = (const float*)d_in[12];
  const float* b2   = (const float*)d_in[13];
  const float* ln2g = (const float*)d_in[14];
  const float* ln2b = (const float*)d_in[15];
  const float* Wlin = (const float*)d_in[16];
  const float* blin = (const float*)d_in[17];
  const float* Wtab = (const float*)d_in[18];
  const float* btab = (const float*)d_in[19];
  const float* Widx = (const float*)d_in[20];
  const float* bidx = (const float*)d_in[21];
  float* out = (float*)d_out;
  char*  ws  = (char*)d_ws;

  const size_t off_x    = 0;                 // 25600*128 bf16 = 6,553,600
  const size_t off_qkv  = 6553600;           // 25600*384 bf16 = 19,660,800 (o2 aliases)
  const size_t off_attn = 26214400;          // 25600*128 bf16
  const size_t off_hcat = 32768000;          // 128*256 bf16
  const size_t off_h    = off_hcat + 65536;  // 128*512 bf16
  const size_t off_wimg = 33030144;          // 128 chunks * 36096 B = 4,620,288

  unsigned short* x    = (unsigned short*)(ws + off_x);
  unsigned short* qkv  = (unsigned short*)(ws + off_qkv);
  unsigned short* o2   = qkv;                       // reuse (qkv dead after attn)
  unsigned short* attn = (unsigned short*)(ws + off_attn);
  unsigned short* hcat = (unsigned short*)(ws + off_hcat);
  unsigned short* h    = (unsigned short*)(ws + off_h);
  unsigned short* wimg = (unsigned short*)(ws + off_wimg);

  prep_kernel<<<128, 256, 0, stream>>>(W1, b1, W2, wimg);

  for (int e = 0; e < 2; e++) {
    gather_kernel<<<25600, 128, 0, stream>>>(
        e == 0 ? tab_ids : idx_ids,
        e == 0 ? table_embed : idx_embed, x);
    for (int l = 0; l < 2; l++) {
      int pi = e * 2 + l;
      gemm(stream, x, 128, Wqkv + (size_t)pi * 384 * 128, 128,
           bqkv + (size_t)pi * 384, qkv, nullptr, 25600, 384, 128, 384, 0);
      attn_kernel<<<1024, 256, 0, stream>>>(qkv, attn);
      gemm(stream, attn, 128, Wo + (size_t)pi * 128 * 128, 128,
           bo + (size_t)pi * 128, o2, nullptr, 25600, 128, 128, 128, 0);
      ln_kernel<<<6400, 256, 0, stream>>>(x, o2, ln1g + pi * 128, ln1b + pi * 128);
      ffn_kernel<<<400, 256, 0, stream>>>(
          x, wimg + (size_t)pi * 32 * CHIM, b2 + pi * 128, o2);
      ln_kernel<<<6400, 256, 0, stream>>>(x, o2, ln2g + pi * 128, ln2b + pi * 128);
    }
    pool_kernel<<<128, 128, 0, stream>>>(x, hcat, e * 128);
  }

  gemm(stream, hcat, 256, Wlin, 256, blin, h, nullptr, 128, 512, 256, 512, 1);
  gemm(stream, h, 512, Wtab, 513, btab, nullptr, out,           128, 1000,   512, 1000,   2);
  gemm(stream, h, 512, Widx, 513, bidx, nullptr, out + 1024000, 128, 100000, 512, 100000, 2);
}

// Round 3
// 1296.175 us; speedup vs baseline: 2.2783x; 1.2012x over previous
//
#include <hip/hip_runtime.h>

typedef __bf16 bf16x8 __attribute__((ext_vector_type(8)));
typedef float floatx4 __attribute__((ext_vector_type(4)));

__device__ __forceinline__ float u2f(unsigned short u) {
  union { unsigned int i; float f; } v; v.i = ((unsigned int)u) << 16; return v.f;
}
__device__ __forceinline__ unsigned short f2b(float f) {
  union { float f; unsigned int i; } v; v.f = f;
  unsigned int r = (v.i + 0x7fffu + ((v.i >> 16) & 1u)) >> 16;
  return (unsigned short)r;
}

__device__ __forceinline__ void gl16(const void* g, void* l) {
  __builtin_amdgcn_global_load_lds(
      (const __attribute__((address_space(1))) unsigned int*)g,
      (__attribute__((address_space(3))) unsigned int*)l, 16, 0, 0);
}

// image sizes (ushort units)
#define FCH 18048   // ffn chunk: W1c[64x136]@0, W2c[128x72]@8704, b1c(64 f32)@17920
#define QCH 8832    // qkv chunk: W[64x136]@0, bias(64 f32)@8704
#define OCH 18176   // wo: W[128x136]@0, bo@17408, g@17664, b@17920 (128 f32 each)

// ---------------------------------------------------------------------------
// Generic GEMM (final projections only): C = A[M,K](bf16) @ W[N,K](f32)^T + b
// mode 1: relu->bf16; mode 2: heads epilogue (fp32, 8 t-steps)
// ---------------------------------------------------------------------------
#define LDS_STRIDE 48

__global__ __launch_bounds__(256) void gemm_kernel(
    const unsigned short* __restrict__ A, int lda,
    const float* __restrict__ W, int ldw,
    const float* __restrict__ bias,
    unsigned short* __restrict__ outB, float* __restrict__ outF,
    int M, int N, int K, int ldc, int mode)
{
  __shared__ unsigned short As[128 * LDS_STRIDE];
  __shared__ unsigned short Bs[128 * LDS_STRIDE];

  const int tid  = threadIdx.x;
  const int m0   = blockIdx.y * 128;
  const int n0   = blockIdx.x * 128;
  const int wave = tid >> 6;
  const int lane = tid & 63;
  const int wm   = (wave >> 1) * 64;
  const int wn   = (wave & 1) * 64;
  const int lr   = lane & 15;
  const int lq   = lane >> 4;

  floatx4 acc[4][4];
#pragma unroll
  for (int i = 0; i < 4; i++)
#pragma unroll
    for (int j = 0; j < 4; j++)
      acc[i][j] = (floatx4){0.f, 0.f, 0.f, 0.f};

  for (int k0 = 0; k0 < K; k0 += 32) {
    __syncthreads();
#pragma unroll
    for (int i = 0; i < 2; i++) {
      int c   = tid + i * 256;
      int row = c >> 2;
      int k8  = (c & 3) * 8;
      uint4 val = {0u, 0u, 0u, 0u};
      if (m0 + row < M)
        val = *(const uint4*)(A + (size_t)(m0 + row) * lda + k0 + k8);
      *(uint4*)(&As[row * LDS_STRIDE + k8]) = val;
    }
#pragma unroll
    for (int i = 0; i < 4; i++) {
      int c   = tid + i * 256;
      int row = c >> 3;
      int k4  = (c & 7) * 4;
      float f0 = 0.f, f1 = 0.f, f2 = 0.f, f3 = 0.f;
      if (n0 + row < N) {
        const float* p = W + (size_t)(n0 + row) * ldw + k0 + k4;
        f0 = p[0]; f1 = p[1]; f2 = p[2]; f3 = p[3];
      }
      ushort4 pk;
      pk.x = f2b(f0); pk.y = f2b(f1); pk.z = f2b(f2); pk.w = f2b(f3);
      *(ushort4*)(&Bs[row * LDS_STRIDE + k4]) = pk;
    }
    __syncthreads();

    bf16x8 af[4], bfr[4];
#pragma unroll
    for (int t = 0; t < 4; t++) {
      af[t]  = *(const bf16x8*)(&As[(wm + t * 16 + lr) * LDS_STRIDE + lq * 8]);
      bfr[t] = *(const bf16x8*)(&Bs[(wn + t * 16 + lr) * LDS_STRIDE + lq * 8]);
    }
#pragma unroll
    for (int tm = 0; tm < 4; tm++)
#pragma unroll
      for (int tn = 0; tn < 4; tn++)
        acc[tm][tn] = __builtin_amdgcn_mfma_f32_16x16x32_bf16(
            af[tm], bfr[tn], acc[tm][tn], 0, 0, 0);
  }

#pragma unroll
  for (int tm = 0; tm < 4; tm++) {
#pragma unroll
    for (int tn = 0; tn < 4; tn++) {
      int gcol = n0 + wn + tn * 16 + lr;
      if (gcol >= N) continue;
      float bs = bias[gcol];
      if (mode == 2) {
        float wl = W[(size_t)gcol * ldw + K];
#pragma unroll
        for (int r = 0; r < 4; r++) {
          int grow = m0 + wm + tm * 16 + lq * 4 + r;
          float base = acc[tm][tn][r] + bs;
          float* op = outF + ((size_t)grow * 8) * (size_t)N + gcol;
#pragma unroll
          for (int t = 0; t < 8; t++)
            op[(size_t)t * N] = base + (float)t * wl;
        }
      } else {
#pragma unroll
        for (int r = 0; r < 4; r++) {
          int grow = m0 + wm + tm * 16 + lq * 4 + r;
          if (grow < M) {
            float v = acc[tm][tn][r] + bs;
            if (mode == 1) v = fmaxf(v, 0.f);
            outB[(size_t)grow * ldc + gcol] = f2b(v);
          }
        }
      }
    }
  }
}

// ---------------------------------------------------------------------------
// MFMA attention: one block per (b,h). S=200, hd=16.  (unchanged)
// ---------------------------------------------------------------------------
#define QKSTR 40
#define PSTR  232

__global__ __launch_bounds__(256) void attn_kernel(
    const unsigned short* __restrict__ qkv, unsigned short* __restrict__ out)
{
  __shared__ __attribute__((aligned(16))) unsigned short qsh[208 * QKSTR];
  __shared__ __attribute__((aligned(16))) unsigned short ksh[208 * QKSTR];
  __shared__ __attribute__((aligned(16))) unsigned short vsh[16 * PSTR];
  __shared__ __attribute__((aligned(16))) unsigned short psh[4][16 * PSTR];

  const int bh   = blockIdx.x;
  const int b    = bh >> 3, h = bh & 7;
  const int tid  = threadIdx.x;
  const int wave = tid >> 6;
  const int lane = tid & 63;
  const int lr   = lane & 15;
  const int lq   = lane >> 4;
  const size_t rowbase = (size_t)b * 200;

  for (int i = tid; i < 208 * QKSTR / 2; i += 256) {
    ((unsigned int*)qsh)[i] = 0u;
    ((unsigned int*)ksh)[i] = 0u;
  }
  for (int i = tid; i < 16 * PSTR / 2; i += 256)
    ((unsigned int*)vsh)[i] = 0u;
  for (int i = tid; i < 4 * 16 * PSTR / 2; i += 256)
    ((unsigned int*)&psh[0][0])[i] = 0u;
  __syncthreads();

  for (int i = tid; i < 800; i += 256) {
    int s = i >> 2, d4 = (i & 3) * 4;
    const unsigned short* base = qkv + (rowbase + s) * 384 + h * 16 + d4;
    uint2 qv = *(const uint2*)(base);
    uint2 kv = *(const uint2*)(base + 128);
    uint2 vv = *(const uint2*)(base + 256);
    *(uint2*)&qsh[s * QKSTR + d4] = qv;
    *(uint2*)&ksh[s * QKSTR + d4] = kv;
    vsh[(d4 + 0) * PSTR + s] = (unsigned short)(vv.x & 0xffffu);
    vsh[(d4 + 1) * PSTR + s] = (unsigned short)(vv.x >> 16);
    vsh[(d4 + 2) * PSTR + s] = (unsigned short)(vv.y & 0xffffu);
    vsh[(d4 + 3) * PSTR + s] = (unsigned short)(vv.y >> 16);
  }
  __syncthreads();

  unsigned short* pw = &psh[wave][0];

  for (int t = wave; t < 13; t += 4) {
    const int q0 = t * 16;
    bf16x8 qf = *(const bf16x8*)&qsh[(q0 + lr) * QKSTR + lq * 8];

    floatx4 s[13];
#pragma unroll
    for (int c = 0; c < 13; c++) {
      bf16x8 kf = *(const bf16x8*)&ksh[(c * 16 + lr) * QKSTR + lq * 8];
      s[c] = __builtin_amdgcn_mfma_f32_16x16x32_bf16(
          qf, kf, (floatx4){0.f, 0.f, 0.f, 0.f}, 0, 0, 0);
    }

    float mx[4] = {-1e30f, -1e30f, -1e30f, -1e30f};
#pragma unroll
    for (int c = 0; c < 13; c++)
#pragma unroll
      for (int r = 0; r < 4; r++) {
        float v = s[c][r] * 0.25f;
        if (c == 12 && lr >= 8) v = -1e30f;
        s[c][r] = v;
        mx[r] = fmaxf(mx[r], v);
      }
#pragma unroll
    for (int m = 1; m < 16; m <<= 1)
#pragma unroll
      for (int r = 0; r < 4; r++)
        mx[r] = fmaxf(mx[r], __shfl_xor(mx[r], m, 16));

    float sm[4] = {0.f, 0.f, 0.f, 0.f};
#pragma unroll
    for (int c = 0; c < 13; c++)
#pragma unroll
      for (int r = 0; r < 4; r++) {
        float e = __expf(s[c][r] - mx[r]);
        s[c][r] = e;
        sm[r] += e;
      }
#pragma unroll
    for (int m = 1; m < 16; m <<= 1)
#pragma unroll
      for (int r = 0; r < 4; r++)
        sm[r] += __shfl_xor(sm[r], m, 16);

#pragma unroll
    for (int c = 0; c < 13; c++)
#pragma unroll
      for (int r = 0; r < 4; r++)
        pw[(lq * 4 + r) * PSTR + c * 16 + lr] = f2b(s[c][r]);

    floatx4 o = {0.f, 0.f, 0.f, 0.f};
#pragma unroll
    for (int ks = 0; ks < 7; ks++) {
      bf16x8 pf = *(const bf16x8*)&pw[lr * PSTR + ks * 32 + lq * 8];
      bf16x8 vf = *(const bf16x8*)&vsh[lr * PSTR + ks * 32 + lq * 8];
      o = __builtin_amdgcn_mfma_f32_16x16x32_bf16(pf, vf, o, 0, 0, 0);
    }

#pragma unroll
    for (int r = 0; r < 4; r++) {
      int q = q0 + lq * 4 + r;
      if (q < 200)
        out[(rowbase + q) * 128 + h * 16 + lr] = f2b(o[r] / sm[r]);
    }
  }
}

// ---------------------------------------------------------------------------
// Weight prepack: bf16 LDS images for ffn chunks, qkv chunks, and Wo(+ln1).
// grid 156: [0,128) ffn (pi*32+c), [128,152) qkv (pi*6+c), [152,156) wo (pi)
// ---------------------------------------------------------------------------
__global__ __launch_bounds__(256) void prep_kernel(
    const float* __restrict__ W1, const float* __restrict__ b1,
    const float* __restrict__ W2,
    const float* __restrict__ Wqkv, const float* __restrict__ bqkv,
    const float* __restrict__ Wo, const float* __restrict__ bo,
    const float* __restrict__ ln1g, const float* __restrict__ ln1b,
    unsigned short* __restrict__ fimg, unsigned short* __restrict__ qimg,
    unsigned short* __restrict__ oimg)
{
  const int blk = blockIdx.x;
  const int tid = threadIdx.x;
  if (blk < 128) {
    const int pi = blk >> 5, c = blk & 31;
    unsigned short* o = fimg + (size_t)blk * FCH;
    const float* w1 = W1 + ((size_t)pi * 2048 + c * 64) * 128;
    const float* w2 = W2 + (size_t)pi * 128 * 2048 + c * 64;
    for (int u = tid; u < 64 * 34; u += 256) {
      int row = u / 34, c4 = (u % 34) * 4;
      ushort4 pk = {0, 0, 0, 0};
      if (c4 < 128) {
        const float* p = w1 + row * 128 + c4;
        pk.x = f2b(p[0]); pk.y = f2b(p[1]); pk.z = f2b(p[2]); pk.w = f2b(p[3]);
      }
      *(ushort4*)&o[row * 136 + c4] = pk;
    }
    for (int u = tid; u < 128 * 18; u += 256) {
      int row = u / 18, c4 = (u % 18) * 4;
      ushort4 pk = {0, 0, 0, 0};
      if (c4 < 64) {
        const float* p = w2 + (size_t)row * 2048 + c4;
        pk.x = f2b(p[0]); pk.y = f2b(p[1]); pk.z = f2b(p[2]); pk.w = f2b(p[3]);
      }
      *(ushort4*)&o[8704 + row * 72 + c4] = pk;
    }
    if (tid < 64)
      ((float*)(o + 17920))[tid] = b1[(size_t)pi * 2048 + c * 64 + tid];
  } else if (blk < 152) {
    const int q = blk - 128;
    const int pi = q / 6, c = q % 6;
    unsigned short* o = qimg + (size_t)q * QCH;
    const float* w = Wqkv + ((size_t)pi * 384 + c * 64) * 128;
    for (int u = tid; u < 64 * 34; u += 256) {
      int row = u / 34, c4 = (u % 34) * 4;
      ushort4 pk = {0, 0, 0, 0};
      if (c4 < 128) {
        const float* p = w + row * 128 + c4;
        pk.x = f2b(p[0]); pk.y = f2b(p[1]); pk.z = f2b(p[2]); pk.w = f2b(p[3]);
      }
      *(ushort4*)&o[row * 136 + c4] = pk;
    }
    if (tid < 64)
      ((float*)(o + 8704))[tid] = bqkv[(size_t)pi * 384 + c * 64 + tid];
  } else {
    const int pi = blk - 152;
    unsigned short* o = oimg + (size_t)pi * OCH;
    const float* w = Wo + (size_t)pi * 128 * 128;
    for (int u = tid; u < 128 * 34; u += 256) {
      int row = u / 34, c4 = (u % 34) * 4;
      ushort4 pk = {0, 0, 0, 0};
      if (c4 < 128) {
        const float* p = w + row * 128 + c4;
        pk.x = f2b(p[0]); pk.y = f2b(p[1]); pk.z = f2b(p[2]); pk.w = f2b(p[3]);
      }
      *(ushort4*)&o[row * 136 + c4] = pk;
    }
    if (tid < 128) {
      ((float*)(o + 17408))[tid] = bo[(size_t)pi * 128 + tid];
      ((float*)(o + 17664))[tid] = ln1g[(size_t)pi * 128 + tid];
      ((float*)(o + 17920))[tid] = ln1b[(size_t)pi * 128 + tid];
    }
  }
}

// ---------------------------------------------------------------------------
// QKV: out[25600,384] = x[25600,128] @ Wqkv^T + bqkv (bf16 out)
// 64-row tiles (grid 400), 6 N-chunks of 64, double-buffered gl16, vmcnt(5).
// ---------------------------------------------------------------------------
__global__ __launch_bounds__(256) void qkv_kernel(
    const unsigned short* __restrict__ x,
    const unsigned short* __restrict__ wimg,   // 6 * QCH
    unsigned short* __restrict__ out)
{
  __shared__ __attribute__((aligned(16))) unsigned short wbuf[2][QCH];

  const int tid  = threadIdx.x;
  const int wave = tid >> 6;
  const int lane = tid & 63;
  const int lr   = lane & 15;
  const int lq   = lane >> 4;
  const int m0   = blockIdx.x * 64;
  const int wm   = wave * 16;

  bf16x8 af[4];
#pragma unroll
  for (int ks = 0; ks < 4; ks++)
    af[ks] = *(const bf16x8*)(x + (size_t)(m0 + wm + lr) * 128 + ks * 32 + lq * 8);

#pragma unroll
  for (int i = 0; i < 5; i++) {
    int u = tid + i * 256;
    if (u < 1104) gl16(wimg + (size_t)u * 8, &wbuf[0][(size_t)u * 8]);
  }

  for (int c = 0; c < 6; c++) {
    if (c + 1 < 6) {
      const unsigned short* src = wimg + (size_t)(c + 1) * QCH;
      unsigned short* dst = &wbuf[(c + 1) & 1][0];
#pragma unroll
      for (int i = 0; i < 5; i++) {
        int u = tid + i * 256;
        if (u < 1104) gl16(src + (size_t)u * 8, dst + (size_t)u * 8);
      }
      asm volatile("s_waitcnt vmcnt(5)" ::: "memory");
    } else {
      asm volatile("s_waitcnt vmcnt(0)" ::: "memory");
    }
    __builtin_amdgcn_s_barrier();
    __builtin_amdgcn_sched_barrier(0);

    const unsigned short* wb = &wbuf[c & 1][0];

    floatx4 acc[4];
#pragma unroll
    for (int tn = 0; tn < 4; tn++) acc[tn] = (floatx4){0.f, 0.f, 0.f, 0.f};
#pragma unroll
    for (int ks = 0; ks < 4; ks++)
#pragma unroll
      for (int tn = 0; tn < 4; tn++) {
        bf16x8 wf = *(const bf16x8*)&wb[(tn * 16 + lr) * 136 + ks * 32 + lq * 8];
        acc[tn] = __builtin_amdgcn_mfma_f32_16x16x32_bf16(af[ks], wf, acc[tn], 0, 0, 0);
      }
    const float* bc = (const float*)(wb + 8704);
#pragma unroll
    for (int tn = 0; tn < 4; tn++) {
      float bb = bc[tn * 16 + lr];
#pragma unroll
      for (int r = 0; r < 4; r++) {
        int row = m0 + wm + lq * 4 + r;
        out[(size_t)row * 384 + c * 64 + tn * 16 + lr] = f2b(acc[tn][r] + bb);
      }
    }
    __builtin_amdgcn_s_barrier();
  }
}

// ---------------------------------------------------------------------------
// Wo + residual + LN1 fused: x = LN(x + attn @ Wo^T + bo) * g + b
// 64-row tiles (grid 400); Wo image staged once via gl16 (36 KB LDS).
// Row r lives in the 16 lanes of one lq-group -> 16-wide shfl reduction.
// ---------------------------------------------------------------------------
__global__ __launch_bounds__(256) void wo_ln_kernel(
    const unsigned short* __restrict__ attn,
    const unsigned short* __restrict__ wimg,   // OCH
    unsigned short* __restrict__ x)
{
  __shared__ __attribute__((aligned(16))) unsigned short wbuf[OCH];

  const int tid  = threadIdx.x;
  const int wave = tid >> 6;
  const int lane = tid & 63;
  const int lr   = lane & 15;
  const int lq   = lane >> 4;
  const int m0   = blockIdx.x * 64;
  const int wm   = wave * 16;

#pragma unroll
  for (int i = 0; i < 9; i++) {
    int u = tid + i * 256;
    if (u < 2272) gl16(wimg + (size_t)u * 8, &wbuf[(size_t)u * 8]);
  }

  bf16x8 af[4];
#pragma unroll
  for (int ks = 0; ks < 4; ks++)
    af[ks] = *(const bf16x8*)(attn + (size_t)(m0 + wm + lr) * 128 + ks * 32 + lq * 8);

  asm volatile("s_waitcnt vmcnt(0)" ::: "memory");
  __builtin_amdgcn_s_barrier();
  __builtin_amdgcn_sched_barrier(0);

  floatx4 acc[8];
#pragma unroll
  for (int i = 0; i < 8; i++) acc[i] = (floatx4){0.f, 0.f, 0.f, 0.f};
#pragma unroll
  for (int ks = 0; ks < 4; ks++)
#pragma unroll
    for (int tn = 0; tn < 8; tn++) {
      bf16x8 wf = *(const bf16x8*)&wbuf[(tn * 16 + lr) * 136 + ks * 32 + lq * 8];
      acc[tn] = __builtin_amdgcn_mfma_f32_16x16x32_bf16(af[ks], wf, acc[tn], 0, 0, 0);
    }

  const float* bo = (const float*)(wbuf + 17408);
  const float* g  = (const float*)(wbuf + 17664);
  const float* bb = (const float*)(wbuf + 17920);

  float v[8][4];
  float s[4] = {0.f, 0.f, 0.f, 0.f}, ss[4] = {0.f, 0.f, 0.f, 0.f};
#pragma unroll
  for (int tn = 0; tn < 8; tn++) {
    float bsv = bo[tn * 16 + lr];
#pragma unroll
    for (int r = 0; r < 4; r++) {
      size_t idx = (size_t)(m0 + wm + lq * 4 + r) * 128 + tn * 16 + lr;
      float t = acc[tn][r] + bsv + u2f(x[idx]);
      v[tn][r] = t;
      s[r] += t;
      ss[r] += t * t;
    }
  }
#pragma unroll
  for (int m = 1; m < 16; m <<= 1)
#pragma unroll
    for (int r = 0; r < 4; r++) {
      s[r]  += __shfl_xor(s[r], m, 16);
      ss[r] += __shfl_xor(ss[r], m, 16);
    }
  float mean[4], rstd[4];
#pragma unroll
  for (int r = 0; r < 4; r++) {
    mean[r] = s[r] * (1.f / 128.f);
    float var = ss[r] * (1.f / 128.f) - mean[r] * mean[r];
    rstd[r] = rsqrtf(var + 1e-5f);
  }
#pragma unroll
  for (int tn = 0; tn < 8; tn++) {
    int col = tn * 16 + lr;
    float gv = g[col], bv = bb[col];
#pragma unroll
    for (int r = 0; r < 4; r++) {
      size_t idx = (size_t)(m0 + wm + lq * 4 + r) * 128 + col;
      x[idx] = f2b((v[tn][r] - mean[r]) * rstd[r] * gv + bv);
    }
  }
}

// ---------------------------------------------------------------------------
// Fused FFN + residual + LN2: x = LN(x + ffn(x)) * g + b   (in place)
// 64-row tiles (grid 400), 32 chunks, double-buffered gl16, vmcnt(9).
// ---------------------------------------------------------------------------
__global__ __launch_bounds__(256) void ffn_kernel(
    const unsigned short* __restrict__ xin,
    const unsigned short* __restrict__ wimg,   // 32 * FCH
    const float* __restrict__ b2,
    const float* __restrict__ g2, const float* __restrict__ bb2,
    unsigned short* __restrict__ x)
{
  __shared__ __attribute__((aligned(16))) unsigned short wbuf[2][FCH];
  __shared__ __attribute__((aligned(16))) unsigned short mids[64 * 72];

  const int tid  = threadIdx.x;
  const int wave = tid >> 6;
  const int lane = tid & 63;
  const int lr   = lane & 15;
  const int lq   = lane >> 4;
  const int m0   = blockIdx.x * 64;
  const int wm   = wave * 16;

  bf16x8 af[4];
#pragma unroll
  for (int ks = 0; ks < 4; ks++)
    af[ks] = *(const bf16x8*)(xin + (size_t)(m0 + wm + lr) * 128 + ks * 32 + lq * 8);

  floatx4 acc[8];
#pragma unroll
  for (int i = 0; i < 8; i++) acc[i] = (floatx4){0.f, 0.f, 0.f, 0.f};

#pragma unroll
  for (int i = 0; i < 9; i++) {
    int u = tid + i * 256;
    if (u < 2256) gl16(wimg + (size_t)u * 8, &wbuf[0][(size_t)u * 8]);
  }

  for (int c = 0; c < 32; c++) {
    if (c + 1 < 32) {
      const unsigned short* src = wimg + (size_t)(c + 1) * FCH;
      unsigned short* dst = &wbuf[(c + 1) & 1][0];
#pragma unroll
      for (int i = 0; i < 9; i++) {
        int u = tid + i * 256;
        if (u < 2256) gl16(src + (size_t)u * 8, dst + (size_t)u * 8);
      }
      asm volatile("s_waitcnt vmcnt(9)" ::: "memory");
    } else {
      asm volatile("s_waitcnt vmcnt(0)" ::: "memory");
    }
    __builtin_amdgcn_s_barrier();
    __builtin_amdgcn_sched_barrier(0);

    const unsigned short* wb = &wbuf[c & 1][0];

    floatx4 macc[4];
#pragma unroll
    for (int tn = 0; tn < 4; tn++) macc[tn] = (floatx4){0.f, 0.f, 0.f, 0.f};
#pragma unroll
    for (int ks = 0; ks < 4; ks++)
#pragma unroll
      for (int tn = 0; tn < 4; tn++) {
        bf16x8 wf = *(const bf16x8*)&wb[(tn * 16 + lr) * 136 + ks * 32 + lq * 8];
        macc[tn] = __builtin_amdgcn_mfma_f32_16x16x32_bf16(af[ks], wf, macc[tn], 0, 0, 0);
      }
    const float* b1c = (const float*)(wb + 17920);
#pragma unroll
    for (int tn = 0; tn < 4; tn++) {
      float bb = b1c[tn * 16 + lr];
#pragma unroll
      for (int r = 0; r < 4; r++) {
        float v = fmaxf(macc[tn][r] + bb, 0.f);
        mids[(wm + lq * 4 + r) * 72 + tn * 16 + lr] = f2b(v);
      }
    }
#pragma unroll
    for (int ks = 0; ks < 2; ks++) {
      bf16x8 mf = *(const bf16x8*)&mids[(wm + lr) * 72 + ks * 32 + lq * 8];
#pragma unroll
      for (int tn = 0; tn < 8; tn++) {
        bf16x8 wf = *(const bf16x8*)&wb[8704 + (tn * 16 + lr) * 72 + ks * 32 + lq * 8];
        acc[tn] = __builtin_amdgcn_mfma_f32_16x16x32_bf16(mf, wf, acc[tn], 0, 0, 0);
      }
    }
    __builtin_amdgcn_s_barrier();
  }

  // epilogue: residual + LN2, write x
  float v[8][4];
  float s[4] = {0.f, 0.f, 0.f, 0.f}, ss[4] = {0.f, 0.f, 0.f, 0.f};
#pragma unroll
  for (int tn = 0; tn < 8; tn++) {
    float bsv = b2[tn * 16 + lr];
#pragma unroll
    for (int r = 0; r < 4; r++) {
      size_t idx = (size_t)(m0 + wm + lq * 4 + r) * 128 + tn * 16 + lr;
      float t = acc[tn][r] + bsv + u2f(x[idx]);
      v[tn][r] = t;
      s[r] += t;
      ss[r] += t * t;
    }
  }
#pragma unroll
  for (int m = 1; m < 16; m <<= 1)
#pragma unroll
    for (int r = 0; r < 4; r++) {
      s[r]  += __shfl_xor(s[r], m, 16);
      ss[r] += __shfl_xor(ss[r], m, 16);
    }
  float mean[4], rstd[4];
#pragma unroll
  for (int r = 0; r < 4; r++) {
    mean[r] = s[r] * (1.f / 128.f);
    float var = ss[r] * (1.f / 128.f) - mean[r] * mean[r];
    rstd[r] = rsqrtf(var + 1e-5f);
  }
#pragma unroll
  for (int tn = 0; tn < 8; tn++) {
    int col = tn * 16 + lr;
    float gv = g2[col], bv = bb2[col];
#pragma unroll
    for (int r = 0; r < 4; r++) {
      size_t idx = (size_t)(m0 + wm + lq * 4 + r) * 128 + col;
      x[idx] = f2b((v[tn][r] - mean[r]) * rstd[r] * gv + bv);
    }
  }
}

// ---------------------------------------------------------------------------
__global__ __launch_bounds__(256) void gather_kernel(
    const int* __restrict__ ids, const float* __restrict__ table,
    unsigned short* __restrict__ x)
{
  int t0 = blockIdx.x * 256 + threadIdx.x;
#pragma unroll
  for (int i = 0; i < 4; i++) {
    int u = t0 + i * 409600;
    int row = u >> 6, dp = (u & 63) << 1;
    int id = ids[row];
    const float* p = table + (size_t)id * 128 + dp;
    float f0 = p[0], f1 = p[1];
    ((unsigned int*)x)[u] = (unsigned int)f2b(f0) | ((unsigned int)f2b(f1) << 16);
  }
}

__global__ __launch_bounds__(512) void pool_kernel(
    const unsigned short* __restrict__ x, unsigned short* __restrict__ hcat,
    int col0)
{
  __shared__ float part[512];
  int b = blockIdx.x;
  int d = threadIdx.x & 127;
  int g = threadIdx.x >> 7;
  float s = 0.f;
  for (int t = 0; t < 50; t++)
    s += u2f(x[(size_t)(b * 200 + g * 50 + t) * 128 + d]);
  part[threadIdx.x] = s;
  __syncthreads();
  if (g == 0) {
    float tot = part[d] + part[d + 128] + part[d + 256] + part[d + 384];
    hcat[b * 256 + col0 + d] = f2b(tot * (1.f / 200.f));
  }
}

// ---------------------------------------------------------------------------
static void gemm(hipStream_t st, const unsigned short* A, int lda,
                 const float* W, int ldw, const float* bias,
                 unsigned short* outB, float* outF,
                 int M, int N, int K, int ldc, int mode)
{
  dim3 grid((N + 127) / 128, (M + 127) / 128);
  gemm_kernel<<<grid, dim3(256), 0, st>>>(A, lda, W, ldw, bias, outB, outF,
                                          M, N, K, ldc, mode);
}

extern "C" void kernel_launch(void* const* d_in, const int* in_sizes, int n_in,
                              void* d_out, int out_size, void* d_ws, size_t ws_size,
                              hipStream_t stream)
{
  const int*   tab_ids     = (const int*)d_in[0];
  const int*   idx_ids     = (const int*)d_in[1];
  const float* table_embed = (const float*)d_in[2];
  const float* idx_embed   = (const float*)d_in[3];
  const float* Wqkv = (const float*)d_in[4];
  const float* bqkv = (const float*)d_in[5];
  const float* Wo   = (const float*)d_in[6];
  const float* bo   = (const float*)d_in[7];
  const float* ln1g = (const float*)d_in[8];
  const float* ln1b = (const float*)d_in[9];
  const float* W1   = (const float*)d_in[10];
  const float* b1   = (const float*)d_in[11];
  const float* W2   = (const float*)d_in[12];
  const float* b2   = (const float*)d_in[13];
  const float* ln2g = (const float*)d_in[14];
  const float* ln2b = (const float*)d_in[15];
  const float* Wlin = (const float*)d_in[16];
  const float* blin = (const float*)d_in[17];
  const float* Wtab = (const float*)d_in[18];
  const float* btab = (const float*)d_in[19];
  const float* Widx = (const float*)d_in[20];
  const float* bidx = (const float*)d_in[21];
  float* out = (float*)d_out;
  char*  ws  = (char*)d_ws;

  const size_t off_x    = 0;                 // 25600*128 bf16
  const size_t off_qkv  = 6553600;           // 25600*384 bf16
  const size_t off_attn = 26214400;          // 25600*128 bf16
  const size_t off_hcat = 32768000;          // 128*256 bf16
  const size_t off_h    = off_hcat + 65536;  // 128*512 bf16
  const size_t off_fimg = 33030144;          // 128 * FCH * 2 = 4,620,288
  const size_t off_qimg = off_fimg + (size_t)128 * FCH * 2;   // 24 * QCH * 2
  const size_t off_oimg = off_qimg + (size_t)24 * QCH * 2;    // 4 * OCH * 2

  unsigned short* x    = (unsigned short*)(ws + off_x);
  unsigned short* qkv  = (unsigned short*)(ws + off_qkv);
  unsigned short* attn = (unsigned short*)(ws + off_attn);
  unsigned short* hcat = (unsigned short*)(ws + off_hcat);
  unsigned short* h    = (unsigned short*)(ws + off_h);
  unsigned short* fimg = (unsigned short*)(ws + off_fimg);
  unsigned short* qimg = (unsigned short*)(ws + off_qimg);
  unsigned short* oimg = (unsigned short*)(ws + off_oimg);

  prep_kernel<<<156, 256, 0, stream>>>(W1, b1, W2, Wqkv, bqkv, Wo, bo,
                                       ln1g, ln1b, fimg, qimg, oimg);

  for (int e = 0; e < 2; e++) {
    gather_kernel<<<1600, 256, 0, stream>>>(
        e == 0 ? tab_ids : idx_ids,
        e == 0 ? table_embed : idx_embed, x);
    for (int l = 0; l < 2; l++) {
      int pi = e * 2 + l;
      qkv_kernel<<<400, 256, 0, stream>>>(x, qimg + (size_t)pi * 6 * QCH, qkv);
      attn_kernel<<<1024, 256, 0, stream>>>(qkv, attn);
      wo_ln_kernel<<<400, 256, 0, stream>>>(attn, oimg + (size_t)pi * OCH, x);
      ffn_kernel<<<400, 256, 0, stream>>>(
          x, fimg + (size_t)pi * 32 * FCH, b2 + pi * 128,
          ln2g + pi * 128, ln2b + pi * 128, x);
    }
    pool_kernel<<<128, 512, 0, stream>>>(x, hcat, e * 128);
  }

  gemm(stream, hcat, 256, Wlin, 256, blin, h, nullptr, 128, 512, 256, 512, 1);
  gemm(stream, h, 512, Wtab, 513, btab, nullptr, out,           128, 1000,   512, 1000,   2);
  gemm(stream, h, 512, Widx, 513, bidx, nullptr, out + 1024000, 128, 100000, 512, 100000, 2);
}